// Round 15
// baseline (57.827 us; speedup 1.0000x reference)
//
#include <hip/hip_runtime.h>

#define BATCH 32
#define LATENT 128
#define NODE_DIM 8
#define MAX_NODES 512
#define H_NODE 128
#define H_EDGE 64

typedef _Float16 h2 __attribute__((ext_vector_type(2)));

static __device__ __forceinline__ h2 u32_to_h2(unsigned int x) {
    union { unsigned int u; h2 h; } c; c.u = x; return c.h;
}
static __device__ __forceinline__ unsigned int h2_to_u32(h2 x) {
    union { unsigned int u; h2 h; } c; c.h = x; return c.u;
}

#if __has_builtin(__builtin_amdgcn_fdot2)
#define FDOT2(a, b, c) __builtin_amdgcn_fdot2((a), (b), (c), false)
#else
#define FDOT2(a, b, c) ((c) + (float)(a).x * (float)(b).x + (float)(a).y * (float)(b).y)
#endif

// ws layout: UPKH u32[32][32][512] (2MB) | VH u32[32][512][32] (2MB)
//            | E2H u32[32] | Hws f32[32][128]
#define UPKH_DWORDS (BATCH * 32 * MAX_NODES)
#define VH_DWORDS   (BATCH * MAX_NODES * 32)

// ---------------------------------------------------------------------------
// Kernel 0 (unchanged): h = relu(z@W1+b1) per batch -> ws. 32 blocks.
// ---------------------------------------------------------------------------
__global__ __launch_bounds__(128) void h_gen(
    const float* __restrict__ z, const float* __restrict__ W1,
    const float* __restrict__ b1, float* __restrict__ Hws)
{
    const int b = blockIdx.x, tid = threadIdx.x;
    __shared__ float sz[LATENT];
    sz[tid] = z[b * LATENT + tid];
    __syncthreads();
    float acc = b1[tid];
#pragma unroll 8
    for (int k = 0; k < LATENT; ++k)
        acc += sz[k] * W1[k * H_NODE + tid];
    Hws[b * H_NODE + tid] = fmaxf(acc, 0.0f);
}

// ---------------------------------------------------------------------------
// Kernel 1 (unchanged): nodes (f32, d_out) + U/V packed f16 + E2 packing.
// ---------------------------------------------------------------------------
__global__ __launch_bounds__(256) void gen_nodes_uv(
    const float* __restrict__ Hws, const float* __restrict__ W2,
    const float* __restrict__ b2,  const float* __restrict__ E1,
    const float* __restrict__ eb1, const float* __restrict__ E2,
    float* __restrict__ nodes_out, unsigned int* __restrict__ UPKH,
    unsigned int* __restrict__ VH, unsigned int* __restrict__ E2H)
{
    const int b      = blockIdx.x;
    const int mslice = blockIdx.y;     // 0..15, 256 cols each
    const int tid    = threadIdx.x;    // 0..255
    const int i0     = mslice * 32;    // first node owned by this block

    __shared__ float sh[H_NODE];
    __shared__ float sE1[2 * NODE_DIM][H_EDGE];
    __shared__ float sEb1[H_EDGE];
    __shared__ float sN[32][NODE_DIM];

    if (tid < H_NODE) sh[tid] = Hws[b * H_NODE + tid];
    for (int idx = tid; idx < 2 * NODE_DIM * H_EDGE; idx += 256)
        (&sE1[0][0])[idx] = E1[idx];
    if (tid < H_EDGE) sEb1[tid] = eb1[tid];

    if (b == 0 && mslice == 0 && tid < 32) {
        h2 w = { (_Float16)E2[2 * tid], (_Float16)E2[2 * tid + 1] };
        E2H[tid] = h2_to_u32(w);
    }
    __syncthreads();

    const int m = mslice * 256 + tid;
    float acc = b2[m];
#pragma unroll 8
    for (int k = 0; k < H_NODE; ++k)
        acc += sh[k] * W2[(size_t)k * (MAX_NODES * NODE_DIM) + m];
    nodes_out[(size_t)b * (MAX_NODES * NODE_DIM) + m] = acc;
    sN[tid >> 3][tid & 7] = acc;
    __syncthreads();

    {   // U' -> f16x2, layout [b][c2][i]
        const int il = tid & 31;
        const int cg = tid >> 5;
#pragma unroll
        for (int rep = 0; rep < 4; ++rep) {
            const int c2 = rep * 8 + cg;
            const int c  = 2 * c2;
            float ua = sEb1[c], ub = sEb1[c + 1];
#pragma unroll
            for (int d = 0; d < NODE_DIM; ++d) {
                const float nd = sN[il][d];
                ua += nd * sE1[d][c];
                ub += nd * sE1[d][c + 1];
            }
            h2 uu = { (_Float16)ua, (_Float16)ub };
            UPKH[((size_t)b * 32 + c2) * MAX_NODES + i0 + il] = h2_to_u32(uu);
        }
    }
    {   // V' -> f16x2, layout [b][j][c2] (128B rows)
        const int jl = tid >> 3;
        const int cq = tid & 7;
#pragma unroll
        for (int rep = 0; rep < 4; ++rep) {
            const int c2 = rep * 8 + cq;
            const int c  = 2 * c2;
            float va = 0.f, vb = 0.f;
#pragma unroll
            for (int d = 0; d < NODE_DIM; ++d) {
                const float nd = sN[jl][d];
                va += nd * sE1[NODE_DIM + d][c];
                vb += nd * sE1[NODE_DIM + d][c + 1];
            }
            h2 vv = { (_Float16)va, (_Float16)vb };
            VH[((size_t)(b * MAX_NODES + i0 + jl) << 5) + c2] = h2_to_u32(vv);
        }
    }
}

// ---------------------------------------------------------------------------
// Kernel 2: PROBE build. Byte-identical R10 structure (best: 46.3 total),
// plus a second CSE-proof 64-ch dot per pair (uB = uA ^ 1ulp), result kept
// live by asm volatile. The V registers are reused by the compiler, so the
// added cost is PURE VALU issue (~+5-6us if VALU issues at modeled rate).
// This discriminates: stall-bound (delta~0) vs issue-clean (delta~+5-6) vs
// f16-halfrate (delta>+12).
// ---------------------------------------------------------------------------
__global__ __launch_bounds__(256, 3) void edge_gen(
    const unsigned int* __restrict__ UPKH, const unsigned int* __restrict__ VH,
    const unsigned int* __restrict__ E2H, const float* __restrict__ eb2,
    float* __restrict__ adj)
{
    const int b = blockIdx.y;
    // decode tile: bi in 0..7 (64-wide i), jt in 2*bi..15 (32-wide j)
    int t = blockIdx.x, bi = 0;
    while (t >= 16 - 2 * bi) { t -= 16 - 2 * bi; ++bi; }
    const int jt = 2 * bi + t;
    const bool partial = (jt >> 1) == bi;    // j-window inside i-block

    const int tid  = threadIdx.x;
    const int lane = tid & 63;
    const int wv   = tid >> 6;               // 0..3
    const int i0 = bi * 64, j0 = jt * 32;
    const int i  = i0 + lane;

    __shared__ unsigned int sV[32 * 32];     // 32 rows x 64ch f16 = 4 KB
    __shared__ float P[32][65];              // tile probs for mirror (8.3 KB)

    // stage V tile: 4 KB contiguous, 1 float4 per thread
    {
        const float4* src = (const float4*)(VH + ((size_t)(b * MAX_NODES + j0) << 5));
        ((float4*)sV)[tid] = src[tid];
    }

    // U row for this lane: 32 f16x2 dwords, coalesced per c2
    unsigned int uA[32];
#pragma unroll
    for (int c2 = 0; c2 < 32; ++c2)
        uA[c2] = UPKH[((size_t)b * 32 + c2) * MAX_NODES + i];

    // probe operand: 1-ulp-perturbed copy (defeats CSE; values stay valid f16)
    unsigned int uB[32];
#pragma unroll
    for (int c2 = 0; c2 < 32; ++c2) uB[c2] = uA[c2] ^ 0x00010001u;

    // E2 packed f16x2: 32 uniform dword loads (SGPR path)
    unsigned int wb[32];
#pragma unroll
    for (int c2 = 0; c2 < 32; ++c2) wb[c2] = E2H[c2];

    const float bias = eb2[0];
    float* adjb = adj + (size_t)b * MAX_NODES * MAX_NODES;
    const h2 zh = { (_Float16)0.f, (_Float16)0.f };
    __syncthreads();

#pragma unroll 1
    for (int jj = 0; jj < 8; ++jj) {
        const int jl = wv * 8 + jj;          // 0..31
        const int j  = j0 + jl;
        const float4* vrow = (const float4*)&sV[jl * 32];

        float a0 = 0.f, a1 = 0.f;            // real
        float p0 = 0.f, p1 = 0.f;            // probe
#pragma unroll
        for (int q = 0; q < 8; ++q) {
            union { float4 f4; unsigned int u[4]; } vv;
            vv.f4 = vrow[q];                 // ds_read_b128, uniform
#pragma unroll
            for (int k = 0; k < 4; ++k) {
                const int c2 = 4 * q + k;
                const h2 v = u32_to_h2(vv.u[k]);
                const h2 w = u32_to_h2(wb[c2]);
                h2 s = u32_to_h2(uA[c2]) + v;
                s = __builtin_elementwise_max(s, zh);
                h2 sp = u32_to_h2(uB[c2]) + v;           // probe pass
                sp = __builtin_elementwise_max(sp, zh);
                if (k & 1) { a1 = FDOT2(s, w, a1); p1 = FDOT2(sp, w, p1); }
                else       { a0 = FDOT2(s, w, a0); p0 = FDOT2(sp, w, p0); }
            }
        }
        const float xs = a0 + a1 + bias;
        const float xp = p0 + p1;
        asm volatile("" :: "v"(xp));         // keep probe work live (rule #17)

        const float p = __builtin_amdgcn_rcpf(1.0f + __expf(-xs));

        if (!partial) {
            adjb[(size_t)j * MAX_NODES + i] = p;     // lower half, coalesced
            P[jl][lane] = p;                         // stage for mirror
        } else {
            if (i < j)       { adjb[(size_t)j * MAX_NODES + i] = p;
                               adjb[(size_t)i * MAX_NODES + j] = p; }
            else if (i == j)   adjb[(size_t)j * MAX_NODES + i] = 0.0f;
        }
    }

    if (!partial) {
        __syncthreads();
        // mirror: adj[i0+r][j0..j0+31]; thread owns row r = tid&63, quarter q
        const int r = tid & 63;
        const int q = tid >> 6;              // 0..3
        const size_t rowbase = (size_t)(i0 + r) * MAX_NODES + j0 + q * 8;
        float4 o0, o1;
        o0.x = P[q * 8 + 0][r]; o0.y = P[q * 8 + 1][r];
        o0.z = P[q * 8 + 2][r]; o0.w = P[q * 8 + 3][r];
        o1.x = P[q * 8 + 4][r]; o1.y = P[q * 8 + 5][r];
        o1.z = P[q * 8 + 6][r]; o1.w = P[q * 8 + 7][r];
        *(float4*)&adjb[rowbase]     = o0;
        *(float4*)&adjb[rowbase + 4] = o1;
    }
}

// ---------------------------------------------------------------------------
extern "C" void kernel_launch(void* const* d_in, const int* in_sizes, int n_in,
                              void* d_out, int out_size, void* d_ws, size_t ws_size,
                              hipStream_t stream)
{
    const float* z   = (const float*)d_in[0];
    const float* W1  = (const float*)d_in[1];
    const float* b1  = (const float*)d_in[2];
    const float* W2  = (const float*)d_in[3];
    const float* b2  = (const float*)d_in[4];
    const float* E1  = (const float*)d_in[5];
    const float* eb1 = (const float*)d_in[6];
    const float* E2  = (const float*)d_in[7];
    const float* eb2 = (const float*)d_in[8];

    float* nodes_out = (float*)d_out;                                   // [32,512,8]
    float* adj       = (float*)d_out + BATCH * MAX_NODES * NODE_DIM;    // [32,512,512]

    unsigned int* UPKH = (unsigned int*)d_ws;       // 2 MB
    unsigned int* VHp  = UPKH + UPKH_DWORDS;        // 2 MB
    unsigned int* E2H  = VHp + VH_DWORDS;           // 128 B
    float*        Hws  = (float*)(E2H + 32);        // 16 KB

    h_gen<<<BATCH, 128, 0, stream>>>(z, W1, b1, Hws);

    dim3 g1(BATCH, 16);
    gen_nodes_uv<<<g1, 256, 0, stream>>>(Hws, W2, b2, E1, eb1, E2,
                                         nodes_out, UPKH, VHp, E2H);

    dim3 g2(72, BATCH);
    edge_gen<<<g2, 256, 0, stream>>>(UPKH, VHp, E2H, eb2, adj);
}